// Round 8
// baseline (1135.508 us; speedup 1.0000x reference)
//
#include <hip/hip_runtime.h>
#include <stdint.h>

#define TT 14
#define LL 26
#define EE 128
#define NB 16384
#define NROWS (NB * TT)    // 229376
#define BPB 8              // batches per Viterbi block
#define ROWS (BPB * TT)    // 112 rows per fused-fallback block
#define EPAD 27            // fallback emis pad

// ---------------------------------------------------------------------------
// Setup: fold conv into an effective emission matrix.
//   Weff[e][l] = sum_{ky,kx} conv_w[ky][kx] * Wmat[l][oy*8+ox]
//   be[l]      = conv_b * sum_e Wmat[l][e]
// ---------------------------------------------------------------------------
__global__ __launch_bounds__(256) void crf_setup(
    const float* __restrict__ conv_w, const float* __restrict__ conv_b,
    const float* __restrict__ params, float* __restrict__ weff,
    float* __restrict__ be) {
  int idx = blockIdx.x * 256 + threadIdx.x;
  if (idx < EE * LL) {
    int e = idx / LL, l = idx - e * LL;
    int iy = e >> 3, ix = e & 7;
    float s = 0.f;
    for (int ky = 0; ky < 5; ++ky) {
      int oy = iy - ky + 2;
      if (oy < 0 || oy >= 16) continue;
      for (int kx = 0; kx < 5; ++kx) {
        int ox = ix - kx + 2;
        if (ox < 0 || ox >= 8) continue;
        s += conv_w[ky * 5 + kx] * params[l * EE + oy * 8 + ox];
      }
    }
    weff[e * LL + l] = s;  // [e][l]: consumer reads are wave-uniform
  }
  if (idx < LL) {
    float s = 0.f;
    for (int e = 0; e < EE; ++e) s += params[idx * EE + e];
    be[idx] = conv_b[0] * s;
  }
}

// ---------------------------------------------------------------------------
// Kernel G: emission GEMM. Block = 64 rows, 256 threads.
// Stage: unconditional, fully coalesced (wave reads 1024 B contiguous).
// Compute: wave-uniform 4-way label split (7/7/6/6); per-label K-chain is
// bit-identical to the verified lineage (ascending e-quads, x/y/z/w order).
// ---------------------------------------------------------------------------
__global__ __launch_bounds__(256, 4) void crf_gemm(
    const float* __restrict__ X, const float* __restrict__ weff,
    const float* __restrict__ be, float* __restrict__ emis_g) {
  __shared__ float4 tile[64 * 33];  // pad 33: bank-complete both phases
  const int tid = threadIdx.x;
  const size_t r0 = (size_t)blockIdx.x * 64;
  const float4* X4 = reinterpret_cast<const float4*>(X);

#pragma unroll
  for (int k = 0; k < 8; ++k) {
    int fid = k * 256 + tid;          // 2048 quads = 64 rows x 32, no guard
    int row = fid >> 5, q = fid & 31;
    tile[row * 33 + q] = X4[(r0 + row) * 32 + q];
  }
  __syncthreads();

  const int row = tid & 63;
  const int wv = tid >> 6;                   // wave-uniform quarter
  const int lb = wv * 7 - (wv == 3 ? 1 : 0); // 0,7,14,20
  const int nl = (wv < 2) ? 7 : 6;

  float acc[7];
#pragma unroll
  for (int l = 0; l < 7; ++l) acc[l] = 0.f;

#pragma unroll
  for (int q = 0; q < 32; ++q) {
    const float4 v = tile[row * 33 + q];
    const float* w = weff + q * 4 * LL + lb;  // wave-uniform -> s_load
#pragma unroll
    for (int l = 0; l < 7; ++l)               // l=6 of wv>=2 is discarded
      acc[l] += v.x * w[l] + v.y * w[LL + l] + v.z * w[2 * LL + l] +
                v.w * w[3 * LL + l];
  }

  const size_t base = (r0 + row) * LL + lb;
#pragma unroll
  for (int l = 0; l < 7; ++l)
    if (l < nl) emis_g[base + l] = acc[l] + be[lb + l];  // be: s_load
}

// ---------------------------------------------------------------------------
// Kernel V: Viterbi + backtrack. 8 batches/block, 32-lane group per batch,
// lane j = label. Emis prefetched to statically-indexed regs (no serial
// global-load chain in the recurrence).
// ---------------------------------------------------------------------------
__global__ __launch_bounds__(256) void crf_vit(
    const float* __restrict__ emis_g, const float* __restrict__ params,
    float* __restrict__ out) {
  __shared__ unsigned char bp_s[BPB][TT - 1][28];
  const int tid = threadIdx.x;
  const int g = tid >> 5;
  const int b = blockIdx.x * BPB + g;
  const int j = tid & 31;
  const int jj = (j < LL) ? j : (LL - 1);

  const float* Tr = params + LL * EE;
  float Tcol[LL];
#pragma unroll
  for (int i = 0; i < LL; ++i) Tcol[i] = Tr[i * LL + jj];  // Trans[i][j]

  const float* eb = emis_g + (size_t)b * TT * LL;
  float e_t[TT];
#pragma unroll
  for (int t = 0; t < TT; ++t) e_t[t] = eb[t * LL + jj];  // 14 indep loads

  float alpha = e_t[0];
#pragma unroll
  for (int t = 1; t < TT; ++t) {
    float m = -__builtin_inff();
    int bp = 0;
#pragma unroll
    for (int i = 0; i < LL; ++i) {
      float a_i = __shfl(alpha, i, 32);
      float s = a_i + Tcol[i];
      if (s > m) { m = s; bp = i; }          // strict > : first-index tie
    }
    alpha = m + e_t[t];
    if (j < LL) bp_s[g][t - 1][j] = (unsigned char)bp;
  }

  float val = (j < LL) ? alpha : -__builtin_inff();
  int idx = j;
#pragma unroll
  for (int off = 16; off >= 1; off >>= 1) {
    float v2 = __shfl_xor(val, off, 32);
    int i2 = __shfl_xor(idx, off, 32);
    if (v2 > val || (v2 == val && i2 < idx)) { val = v2; idx = i2; }
  }

  __syncthreads();  // bp_s visible

  if (j == 0) {
    out[(size_t)NROWS + b] = val;  // score
    int lbl = idx;
    for (int t = TT - 1; t >= 1; --t) {
      out[(size_t)b * TT + t] = (float)lbl;
      lbl = bp_s[g][t - 1][lbl];
    }
    out[(size_t)b * TT + 0] = (float)lbl;
  }
}

// ---------------------------------------------------------------------------
// Fallback: R1's verified fused kernel (used only if ws_size is too small
// for the emis buffer). 103 us, absmax 0.0.
// ---------------------------------------------------------------------------
__global__ __launch_bounds__(128, 4) void crf_fused(
    const float* __restrict__ X, const float* __restrict__ params,
    const float* __restrict__ weff, const float* __restrict__ be,
    float* __restrict__ out) {
  __shared__ float emis_s[ROWS * EPAD];
  __shared__ unsigned char bp_s[BPB][TT - 1][28];

  const int tid = threadIdx.x;
  const int b0 = blockIdx.x * BPB;

  if (tid < ROWS) {
    const float4* xv =
        reinterpret_cast<const float4*>(X) + (size_t)(b0 * TT + tid) * 32;
    float acc[LL];
#pragma unroll
    for (int l = 0; l < LL; ++l) acc[l] = 0.f;
    for (int c = 0; c < 8; ++c) {
      float4 v0 = xv[c * 4 + 0];
      float4 v1 = xv[c * 4 + 1];
      float4 v2 = xv[c * 4 + 2];
      float4 v3 = xv[c * 4 + 3];
      const float* w = weff + c * 16 * LL;
#pragma unroll
      for (int l = 0; l < LL; ++l)
        acc[l] += v0.x * w[l] + v0.y * w[LL + l] + v0.z * w[2 * LL + l] +
                  v0.w * w[3 * LL + l];
#pragma unroll
      for (int l = 0; l < LL; ++l)
        acc[l] += v1.x * w[4 * LL + l] + v1.y * w[5 * LL + l] +
                  v1.z * w[6 * LL + l] + v1.w * w[7 * LL + l];
#pragma unroll
      for (int l = 0; l < LL; ++l)
        acc[l] += v2.x * w[8 * LL + l] + v2.y * w[9 * LL + l] +
                  v2.z * w[10 * LL + l] + v2.w * w[11 * LL + l];
#pragma unroll
      for (int l = 0; l < LL; ++l)
        acc[l] += v3.x * w[12 * LL + l] + v3.y * w[13 * LL + l] +
                  v3.z * w[14 * LL + l] + v3.w * w[15 * LL + l];
    }
#pragma unroll
    for (int l = 0; l < LL; ++l) emis_s[tid * EPAD + l] = acc[l] + be[l];
  }
  __syncthreads();

  const int lane = tid & 63;
  const int wv = tid >> 6;
  const int j = lane & 31;
  const int hb = lane >> 5;
  const int jj = (j < LL) ? j : (LL - 1);

  const float* Tr = params + LL * EE;
  float Tcol[LL];
#pragma unroll
  for (int i = 0; i < LL; ++i) Tcol[i] = Tr[i * LL + jj];

  for (int p = 0; p < 2; ++p) {
    const int bl = p * 4 + wv * 2 + hb;

    float alpha = emis_s[(bl * TT + 0) * EPAD + jj];
    for (int t = 1; t < TT; ++t) {
      float m = -__builtin_inff();
      int bp = 0;
#pragma unroll
      for (int i = 0; i < LL; ++i) {
        float a_i = __shfl(alpha, i, 32);
        float s = a_i + Tcol[i];
        if (s > m) { m = s; bp = i; }
      }
      alpha = m + emis_s[(bl * TT + t) * EPAD + jj];
      if (j < LL) bp_s[bl][t - 1][j] = (unsigned char)bp;
    }

    float val = (j < LL) ? alpha : -__builtin_inff();
    int idx = j;
#pragma unroll
    for (int off = 16; off >= 1; off >>= 1) {
      float v2 = __shfl_xor(val, off, 32);
      int i2 = __shfl_xor(idx, off, 32);
      if (v2 > val || (v2 == val && i2 < idx)) { val = v2; idx = i2; }
    }

    __syncthreads();

    if (j == 0) {
      const int b = b0 + bl;
      out[(size_t)NROWS + b] = val;
      int lbl = idx;
      for (int t = TT - 1; t >= 1; --t) {
        out[(size_t)b * TT + t] = (float)lbl;
        lbl = bp_s[bl][t - 1][lbl];
      }
      out[(size_t)b * TT + 0] = (float)lbl;
    }
    __syncthreads();
  }
}

extern "C" void kernel_launch(void* const* d_in, const int* in_sizes, int n_in,
                              void* d_out, int out_size, void* d_ws,
                              size_t ws_size, hipStream_t stream) {
  const float* X = (const float*)d_in[0];
  const float* conv_w = (const float*)d_in[1];
  const float* conv_b = (const float*)d_in[2];
  const float* params = (const float*)d_in[3];
  float* out = (float*)d_out;
  float* weff = (float*)d_ws;            // 3328 floats
  float* be = weff + EE * LL;            // 26 floats
  float* emis_g = (float*)d_ws + 4096;   // 229376*26 floats

  const size_t need = 4096 * 4 + (size_t)NROWS * LL * 4;

  hipLaunchKernelGGL(crf_setup, dim3(13), dim3(256), 0, stream, conv_w, conv_b,
                     params, weff, be);
  if (ws_size >= need) {
    hipLaunchKernelGGL(crf_gemm, dim3(NROWS / 64), dim3(256), 0, stream, X,
                       weff, be, emis_g);
    hipLaunchKernelGGL(crf_vit, dim3(NB / BPB), dim3(256), 0, stream, emis_g,
                       params, out);
  } else {
    hipLaunchKernelGGL(crf_fused, dim3(NB / BPB), dim3(128), 0, stream, X,
                       params, weff, be, out);
  }
}

// Round 9
// 911.011 us; speedup vs baseline: 1.2464x; 1.2464x over previous
//
#include <hip/hip_runtime.h>
#include <stdint.h>

#define TT 14
#define LL 26
#define EE 128
#define NB 16384
#define NROWS (NB * TT)    // 229376
#define BPB 8              // batches per Viterbi block
#define ROWS (BPB * TT)    // 112 rows per fused-fallback block
#define EPAD 27            // odd pad -> bank-bijective

// ---------------------------------------------------------------------------
// Setup: fold conv into an effective emission matrix.
//   Weff[e][l] = sum_{ky,kx} conv_w[ky][kx] * Wmat[l][oy*8+ox]
//   be[l]      = conv_b * sum_e Wmat[l][e]
// ---------------------------------------------------------------------------
__global__ __launch_bounds__(256) void crf_setup(
    const float* __restrict__ conv_w, const float* __restrict__ conv_b,
    const float* __restrict__ params, float* __restrict__ weff,
    float* __restrict__ be) {
  int idx = blockIdx.x * 256 + threadIdx.x;
  if (idx < EE * LL) {
    int e = idx / LL, l = idx - e * LL;
    int iy = e >> 3, ix = e & 7;
    float s = 0.f;
    for (int ky = 0; ky < 5; ++ky) {
      int oy = iy - ky + 2;
      if (oy < 0 || oy >= 16) continue;
      for (int kx = 0; kx < 5; ++kx) {
        int ox = ix - kx + 2;
        if (ox < 0 || ox >= 8) continue;
        s += conv_w[ky * 5 + kx] * params[l * EE + oy * 8 + ox];
      }
    }
    weff[e * LL + l] = s;  // [e][l]: consumer reads are wave-uniform
  }
  if (idx < LL) {
    float s = 0.f;
    for (int e = 0; e < EE; ++e) s += params[idx * EE + e];
    be[idx] = conv_b[0] * s;
  }
}

// ---------------------------------------------------------------------------
// Kernel G: emission GEMM. Block = 64 rows, 256 threads, 4-way wave-uniform
// label split (7/7/6/6). XOR-swizzled LDS tile (bank-floor on both phases).
// Outer e-loop ROLLED (R8 lesson: full unroll -> 896-value hoist -> spill);
// inner 4 quads unrolled -> live W window 112 floats (R1-proven scale).
// Per-label FMA chain bit-identical to the verified lineage.
// ---------------------------------------------------------------------------
__global__ __launch_bounds__(256, 4) void crf_gemm(
    const float* __restrict__ X, const float* __restrict__ weff,
    const float* __restrict__ be, float* __restrict__ emis_g) {
  __shared__ float4 tile[64 * 32];  // 32 KB, slot q^(row&7)
  const int tid = threadIdx.x;
  const size_t r0 = (size_t)blockIdx.x * 64;
  const float4* X4 = reinterpret_cast<const float4*>(X);

#pragma unroll
  for (int k = 0; k < 8; ++k) {
    int fid = k * 256 + tid;          // 2048 quads, no guard
    int row = fid >> 5, q = fid & 31;
    tile[row * 32 + (q ^ (row & 7))] = X4[(r0 + row) * 32 + q];
  }
  __syncthreads();

  const int row = tid & 63;
  const int wv = tid >> 6;                   // wave-uniform quarter
  const int lb = wv * 7 - (wv == 3 ? 1 : 0); // 0,7,14,20
  const int nl = (wv < 2) ? 7 : 6;

  float acc[7];
#pragma unroll
  for (int l = 0; l < 7; ++l) acc[l] = 0.f;

  for (int c = 0; c < 8; ++c) {  // ROLLED: bounds the live W window
#pragma unroll
    for (int u = 0; u < 4; ++u) {
      const int q = c * 4 + u;
      const float4 v = tile[row * 32 + (q ^ (row & 7))];
      const float* w = weff + q * 4 * LL + lb;  // wave-uniform -> s_load
#pragma unroll
      for (int l = 0; l < 7; ++l)  // l=6 of wv>=2 discarded at store
        acc[l] += v.x * w[l] + v.y * w[LL + l] + v.z * w[2 * LL + l] +
                  v.w * w[3 * LL + l];
    }
  }

  // Epilogue: acc -> LDS (pad 27, bank-bijective) -> coalesced block store.
  __syncthreads();  // all tile reads done before aliasing
  float* et = (float*)tile;
#pragma unroll
  for (int l = 0; l < 7; ++l)
    if (l < nl) et[row * EPAD + lb + l] = acc[l] + be[lb + l];  // be: s_load
  __syncthreads();
#pragma unroll
  for (int i = 0; i < 7; ++i) {
    int f = i * 256 + tid;
    if (f < 64 * LL) {
      int rr = f / LL, cc = f - rr * LL;
      emis_g[r0 * LL + f] = et[rr * EPAD + cc];  // contiguous 6656 B
    }
  }
}

// ---------------------------------------------------------------------------
// Kernel V: Viterbi + backtrack. 8 batches/block; emis staged to LDS with
// coalesced loads; 32-lane group per batch, lane j = label (R8-validated
// logic, absmax 0.0).
// ---------------------------------------------------------------------------
__global__ __launch_bounds__(256) void crf_vit(
    const float* __restrict__ emis_g, const float* __restrict__ params,
    float* __restrict__ out) {
  __shared__ float es[BPB * TT * LL];  // 2912 floats, 11648 B
  __shared__ unsigned char bp_s[BPB][TT - 1][28];
  const int tid = threadIdx.x;

  const float* eb = emis_g + (size_t)blockIdx.x * (BPB * TT * LL);
#pragma unroll
  for (int i = 0; i < 12; ++i) {
    int f = i * 256 + tid;
    if (f < BPB * TT * LL) es[f] = eb[f];  // coalesced
  }

  const int g = tid >> 5;
  const int b = blockIdx.x * BPB + g;
  const int j = tid & 31;
  const int jj = (j < LL) ? j : (LL - 1);

  const float* Tr = params + LL * EE;
  float Tcol[LL];
#pragma unroll
  for (int i = 0; i < LL; ++i) Tcol[i] = Tr[i * LL + jj];  // Trans[i][j]

  __syncthreads();

  float e_t[TT];
#pragma unroll
  for (int t = 0; t < TT; ++t) e_t[t] = es[(g * TT + t) * LL + jj];

  float alpha = e_t[0];
#pragma unroll
  for (int t = 1; t < TT; ++t) {
    float m = -__builtin_inff();
    int bp = 0;
#pragma unroll
    for (int i = 0; i < LL; ++i) {
      float a_i = __shfl(alpha, i, 32);
      float s = a_i + Tcol[i];
      if (s > m) { m = s; bp = i; }          // strict > : first-index tie
    }
    alpha = m + e_t[t];
    if (j < LL) bp_s[g][t - 1][j] = (unsigned char)bp;
  }

  float val = (j < LL) ? alpha : -__builtin_inff();
  int idx = j;
#pragma unroll
  for (int off = 16; off >= 1; off >>= 1) {
    float v2 = __shfl_xor(val, off, 32);
    int i2 = __shfl_xor(idx, off, 32);
    if (v2 > val || (v2 == val && i2 < idx)) { val = v2; idx = i2; }
  }

  __syncthreads();  // bp_s visible

  if (j == 0) {
    out[(size_t)NROWS + b] = val;  // score
    int lbl = idx;
    for (int t = TT - 1; t >= 1; --t) {
      out[(size_t)b * TT + t] = (float)lbl;
      lbl = bp_s[g][t - 1][lbl];
    }
    out[(size_t)b * TT + 0] = (float)lbl;
  }
}

// ---------------------------------------------------------------------------
// Fallback: R1's verified fused kernel (only if ws too small). 103 us.
// ---------------------------------------------------------------------------
__global__ __launch_bounds__(128, 4) void crf_fused(
    const float* __restrict__ X, const float* __restrict__ params,
    const float* __restrict__ weff, const float* __restrict__ be,
    float* __restrict__ out) {
  __shared__ float emis_s[ROWS * EPAD];
  __shared__ unsigned char bp_s[BPB][TT - 1][28];

  const int tid = threadIdx.x;
  const int b0 = blockIdx.x * BPB;

  if (tid < ROWS) {
    const float4* xv =
        reinterpret_cast<const float4*>(X) + (size_t)(b0 * TT + tid) * 32;
    float acc[LL];
#pragma unroll
    for (int l = 0; l < LL; ++l) acc[l] = 0.f;
    for (int c = 0; c < 8; ++c) {
      float4 v0 = xv[c * 4 + 0];
      float4 v1 = xv[c * 4 + 1];
      float4 v2 = xv[c * 4 + 2];
      float4 v3 = xv[c * 4 + 3];
      const float* w = weff + c * 16 * LL;
#pragma unroll
      for (int l = 0; l < LL; ++l)
        acc[l] += v0.x * w[l] + v0.y * w[LL + l] + v0.z * w[2 * LL + l] +
                  v0.w * w[3 * LL + l];
#pragma unroll
      for (int l = 0; l < LL; ++l)
        acc[l] += v1.x * w[4 * LL + l] + v1.y * w[5 * LL + l] +
                  v1.z * w[6 * LL + l] + v1.w * w[7 * LL + l];
#pragma unroll
      for (int l = 0; l < LL; ++l)
        acc[l] += v2.x * w[8 * LL + l] + v2.y * w[9 * LL + l] +
                  v2.z * w[10 * LL + l] + v2.w * w[11 * LL + l];
#pragma unroll
      for (int l = 0; l < LL; ++l)
        acc[l] += v3.x * w[12 * LL + l] + v3.y * w[13 * LL + l] +
                  v3.z * w[14 * LL + l] + v3.w * w[15 * LL + l];
    }
#pragma unroll
    for (int l = 0; l < LL; ++l) emis_s[tid * EPAD + l] = acc[l] + be[l];
  }
  __syncthreads();

  const int lane = tid & 63;
  const int wv = tid >> 6;
  const int j = lane & 31;
  const int hb = lane >> 5;
  const int jj = (j < LL) ? j : (LL - 1);

  const float* Tr = params + LL * EE;
  float Tcol[LL];
#pragma unroll
  for (int i = 0; i < LL; ++i) Tcol[i] = Tr[i * LL + jj];

  for (int p = 0; p < 2; ++p) {
    const int bl = p * 4 + wv * 2 + hb;

    float alpha = emis_s[(bl * TT + 0) * EPAD + jj];
    for (int t = 1; t < TT; ++t) {
      float m = -__builtin_inff();
      int bp = 0;
#pragma unroll
      for (int i = 0; i < LL; ++i) {
        float a_i = __shfl(alpha, i, 32);
        float s = a_i + Tcol[i];
        if (s > m) { m = s; bp = i; }
      }
      alpha = m + emis_s[(bl * TT + t) * EPAD + jj];
      if (j < LL) bp_s[bl][t - 1][j] = (unsigned char)bp;
    }

    float val = (j < LL) ? alpha : -__builtin_inff();
    int idx = j;
#pragma unroll
    for (int off = 16; off >= 1; off >>= 1) {
      float v2 = __shfl_xor(val, off, 32);
      int i2 = __shfl_xor(idx, off, 32);
      if (v2 > val || (v2 == val && i2 < idx)) { val = v2; idx = i2; }
    }

    __syncthreads();

    if (j == 0) {
      const int b = b0 + bl;
      out[(size_t)NROWS + b] = val;
      int lbl = idx;
      for (int t = TT - 1; t >= 1; --t) {
        out[(size_t)b * TT + t] = (float)lbl;
        lbl = bp_s[bl][t - 1][lbl];
      }
      out[(size_t)b * TT + 0] = (float)lbl;
    }
    __syncthreads();
  }
}

extern "C" void kernel_launch(void* const* d_in, const int* in_sizes, int n_in,
                              void* d_out, int out_size, void* d_ws,
                              size_t ws_size, hipStream_t stream) {
  const float* X = (const float*)d_in[0];
  const float* conv_w = (const float*)d_in[1];
  const float* conv_b = (const float*)d_in[2];
  const float* params = (const float*)d_in[3];
  float* out = (float*)d_out;
  float* weff = (float*)d_ws;            // 3328 floats
  float* be = weff + EE * LL;            // 26 floats
  float* emis_g = (float*)d_ws + 4096;   // 229376*26 floats

  const size_t need = 4096 * 4 + (size_t)NROWS * LL * 4;

  hipLaunchKernelGGL(crf_setup, dim3(13), dim3(256), 0, stream, conv_w, conv_b,
                     params, weff, be);
  if (ws_size >= need) {
    hipLaunchKernelGGL(crf_gemm, dim3(NROWS / 64), dim3(256), 0, stream, X,
                       weff, be, emis_g);
    hipLaunchKernelGGL(crf_vit, dim3(NB / BPB), dim3(256), 0, stream, emis_g,
                       params, out);
  } else {
    hipLaunchKernelGGL(crf_fused, dim3(NB / BPB), dim3(128), 0, stream, X,
                       params, weff, be, out);
  }
}